// Round 4
// baseline (489.390 us; speedup 1.0000x reference)
//
#include <hip/hip_runtime.h>
#include <math.h>

#define H  14
#define C  7
#define HC 98
#define FIN 256
#define NEG_SLOPE 0.2f
#define LOG2E 1.44269504088896f

#define BSHIFT 9
#define BSIZE  512
#define NBUCK_MAX 256

typedef __attribute__((ext_vector_type(8))) short short8;
typedef __attribute__((ext_vector_type(4))) float floatx4;
typedef _Float16 h2 __attribute__((ext_vector_type(2)));

#define WT_ROWS   112            // 98 cols zero-padded to 7*16
#define WT_STRIDE 264            // 256 + 8 pad (bf16 units)
#define XA_STRIDE 40             // 32 + 8 pad (bf16 units)
#define VS_STRIDE 99             // 98 + 1 pad (f32 units)

// f32 -> bf16 bits, round-to-nearest-even (MFMA staging only)
__device__ __forceinline__ unsigned bf16r(float f) {
    unsigned u = __float_as_uint(f);
    return (u + 0x7FFFu + ((u >> 16) & 1u)) >> 16;
}

// ---- fp16 helpers via native _Float16 vectors (no hip_fp16.h dependence) ----
__device__ __forceinline__ h2 u2h(unsigned u) { return __builtin_bit_cast(h2, u); }
__device__ __forceinline__ unsigned hpk(float a, float b) {
    h2 v = { (_Float16)a, (_Float16)b };
    return __builtin_bit_cast(unsigned, v);
}
__device__ __forceinline__ float hhi(unsigned w) {
    unsigned short s = (unsigned short)(w >> 16);
    return (float)__builtin_bit_cast(_Float16, s);
}
// max-combine of packed fp16 pair across lanes (xor mask)
__device__ __forceinline__ h2 hshfl_max(h2 v, int mask) {
    int u = __builtin_bit_cast(int, v);
    int o = __shfl_xor(u, mask, 64);
    return __builtin_elementwise_max(v, u2h((unsigned)o));
}

// ---------------- bucketed CSR construction (no self loops) ----------------

__global__ void k_zero(int* __restrict__ p, int n) {
    int i = blockIdx.x * blockDim.x + threadIdx.x;
    if (i < n) p[i] = 0;
}

__global__ __launch_bounds__(256) void k_hist(const int* __restrict__ ei, int E,
                                              int* __restrict__ gcnt, int nb) {
    __shared__ int hist[NBUCK_MAX];
    const int t = threadIdx.x;
    for (int i = t; i < nb; i += 256) hist[i] = 0;
    __syncthreads();
    const int stride = gridDim.x * 256;
    for (int e = blockIdx.x * 256 + t; e < E; e += stride)
        atomicAdd(&hist[ei[E + e] >> BSHIFT], 1);
    __syncthreads();
    for (int i = t; i < nb; i += 256)
        if (hist[i]) atomicAdd(gcnt + i, hist[i]);
}

__global__ __launch_bounds__(1024) void k_bscan(const int* __restrict__ gcnt,
                                                int* __restrict__ boff, int* __restrict__ bcur,
                                                int* __restrict__ row_ptr, int nb, int N) {
    __shared__ int sd[1024];
    int t = threadIdx.x;
    int own = (t < nb) ? gcnt[t] : 0;
    sd[t] = own;
    __syncthreads();
    #pragma unroll
    for (int off = 1; off < 1024; off <<= 1) {
        int v = (t >= off) ? sd[t - off] : 0;
        __syncthreads();
        sd[t] += v;
        __syncthreads();
    }
    if (t < nb) {
        boff[t + 1] = sd[t];
        bcur[t] = sd[t] - own;          // exclusive
        if (t == nb - 1) row_ptr[N] = sd[t];
    }
    if (t == 0) boff[0] = 0;
}

__global__ __launch_bounds__(256) void k_part(const int* __restrict__ ei, int E,
                                              int* __restrict__ bcur, int2* __restrict__ pedge,
                                              int nb) {
    __shared__ int hist[NBUCK_MAX];
    __shared__ int start[NBUCK_MAX];
    const int t = threadIdx.x;
    const int chunk = (E + gridDim.x - 1) / gridDim.x;
    const int c0 = blockIdx.x * chunk;
    const int c1 = min(c0 + chunk, E);
    for (int i = t; i < nb; i += 256) hist[i] = 0;
    __syncthreads();
    for (int e = c0 + t; e < c1; e += 256)
        atomicAdd(&hist[ei[E + e] >> BSHIFT], 1);
    __syncthreads();
    for (int i = t; i < nb; i += 256) {
        int h = hist[i];
        start[i] = h ? atomicAdd(bcur + i, h) : 0;
        hist[i] = 0;                     // reuse as local cursor
    }
    __syncthreads();
    for (int e = c0 + t; e < c1; e += 256) {
        int s = ei[e], d = ei[E + e];
        int b = d >> BSHIFT;
        int pos = start[b] + atomicAdd(&hist[b], 1);
        pedge[pos] = make_int2(s, d);
    }
}

__global__ __launch_bounds__(512) void k_bcsr(const int2* __restrict__ pedge,
                                              const int* __restrict__ boff,
                                              int* __restrict__ row_ptr, int* __restrict__ col,
                                              int N) {
    __shared__ int cnt[BSIZE];
    __shared__ int sc[BSIZE];
    __shared__ int cur[BSIZE];
    const int b  = blockIdx.x;
    const int t  = threadIdx.x;
    const int e0 = boff[b], e1 = boff[b + 1];
    const int base = b << BSHIFT;
    const int nv = min(BSIZE, N - base);
    cnt[t] = 0;
    __syncthreads();
    for (int e = e0 + t; e < e1; e += 512)
        atomicAdd(&cnt[pedge[e].y - base], 1);
    __syncthreads();
    sc[t] = cnt[t];
    __syncthreads();
    #pragma unroll
    for (int off = 1; off < BSIZE; off <<= 1) {
        int v = (t >= off) ? sc[t - off] : 0;
        __syncthreads();
        sc[t] += v;
        __syncthreads();
    }
    if (t < nv) {
        int excl = sc[t] - cnt[t];
        row_ptr[base + t] = e0 + excl;
        cur[t] = excl;
    }
    __syncthreads();
    for (int e = e0 + t; e < e1; e += 512) {
        int2 r = pedge[e];
        int d = r.y - base;
        int pos = e0 + atomicAdd(&cur[d], 1);
        col[pos] = r.x;
    }
}

// ---------------- layer-1: MFMA projection fused with pack ----------------

__global__ void k_convW(const float* __restrict__ W, unsigned short* __restrict__ WtG) {
    int id = blockIdx.x * blockDim.x + threadIdx.x;   // 112*256
    int n = id >> 8, k = id & 255;
    float v = (n < HC) ? W[k * HC + n] : 0.f;
    WtG[id] = (unsigned short)(__float_as_uint(v) >> 16);  // exact: inputs bf16-rounded
}

// New pack layout (head-split, 2 passes p=0/1):
//   xpack[(p*N + n)*8 + s] (s=0..6) = {7 msg fp16, src-logit*log2e fp16} for head p*7+s
//   slot 7 = pad (never read) -> each node-pass record = 128 B, 2 aligned lines.
// aldst[n*H+h] = dst logit * log2e (f32), unchanged.
__global__ __launch_bounds__(256) void k_proj1_mfma(
    const float* __restrict__ x, const unsigned short* __restrict__ WtG,
    const float* __restrict__ asrc, const float* __restrict__ adst,
    uint4* __restrict__ xpack, float* __restrict__ aldst, int N)
{
    __shared__ unsigned short wt_s[WT_ROWS * WT_STRIDE];  // 59136 B (reused as f32 vals)
    __shared__ unsigned short xa_s[64 * XA_STRIDE];       //  5120 B
    __shared__ float as_s[HC], ad_s[HC];
    float* vals_s = (float*)wt_s;                          // 64*99*4 = 25344 B < 59136
    const int t  = threadIdx.x;
    const int wv = t >> 6;
    const int l  = t & 63;
    const int ln = l & 15;
    const int qd = l >> 4;
    const int rowBase = blockIdx.x * 64;

    #pragma unroll
    for (int i = 0; i < 14; ++i) {
        int f = i * 256 + t;            // uint4 index, 3584 total (32 per row)
        int r = f >> 5, pos = f & 31;
        *(uint4*)(wt_s + r * WT_STRIDE + pos * 8) = ((const uint4*)WtG)[f];
    }
    if (t < HC) { as_s[t] = asrc[t]; ad_s[t] = adst[t]; }

    floatx4 acc[7] = {};

    for (int step = 0; step < 8; ++step) {
        const int k0 = step * 32;
        __syncthreads();
        #pragma unroll
        for (int i = 0; i < 2; ++i) {
            int idx = i * 256 + t;       // 512 float4 total
            int r = idx >> 3, c4 = idx & 7;
            int gr = rowBase + r; if (gr >= N) gr = N - 1;
            float4 v = *(const float4*)(x + (size_t)gr * FIN + k0 + c4 * 4);
            ushort4 u;
            u.x = (unsigned short)(__float_as_uint(v.x) >> 16);
            u.y = (unsigned short)(__float_as_uint(v.y) >> 16);
            u.z = (unsigned short)(__float_as_uint(v.z) >> 16);
            u.w = (unsigned short)(__float_as_uint(v.w) >> 16);
            *(ushort4*)(xa_s + r * XA_STRIDE + c4 * 4) = u;
        }
        __syncthreads();
        short8 a = *(const short8*)(xa_s + ((wv << 4) + ln) * XA_STRIDE + qd * 8);
        #pragma unroll
        for (int ct = 0; ct < 7; ++ct) {
            short8 b = *(const short8*)(wt_s + (ct * 16 + ln) * WT_STRIDE + k0 + qd * 8);
            acc[ct] = __builtin_amdgcn_mfma_f32_16x16x32_bf16(a, b, acc[ct], 0, 0, 0);
        }
    }

    __syncthreads();                    // wt_s dead; reuse as vals_s
    // C/D: col = ln, row = qd*4 + r (local row = wv*16 + qd*4 + r)
    #pragma unroll
    for (int ct = 0; ct < 7; ++ct) {
        int colg = ct * 16 + ln;
        if (colg < HC) {
            #pragma unroll
            for (int r = 0; r < 4; ++r)
                vals_s[((wv << 4) + (qd << 2) + r) * VS_STRIDE + colg] = acc[ct][r];
        }
    }
    __syncthreads();

    // pack: 64 nodes x 14 heads = 896 records
    for (int p = t; p < 64 * H; p += 256) {
        int nl = p / H, h = p - nl * H;
        int gn = rowBase + nl;
        if (gn >= N) break;
        const float* vp = vals_s + nl * VS_STRIDE + h * C;
        float v[C];
        float s1 = 0.f, s2 = 0.f;
        #pragma unroll
        for (int c2 = 0; c2 < C; ++c2) {
            float f = vp[c2];
            v[c2] = f;
            s1 = fmaf(f, as_s[h * C + c2], s1);
            s2 = fmaf(f, ad_s[h * C + c2], s2);
        }
        uint4 pk;
        pk.x = hpk(v[0], v[1]);
        pk.y = hpk(v[2], v[3]);
        pk.z = hpk(v[4], v[5]);
        pk.w = hpk(v[6], s1 * LOG2E);
        int pass = (h >= C) ? 1 : 0;
        int slot = h - pass * C;
        xpack[((size_t)pass * N + gn) * 8 + slot] = pk;
        aldst[(size_t)gn * H + h] = s2 * LOG2E;
    }
}

// ---------------- layer-2 projection + pack (thread per node) ----------------

__global__ __launch_bounds__(256) void k_proj2_pack(
    const float* __restrict__ h1, const float* __restrict__ W,
    const float* __restrict__ asrc, const float* __restrict__ adst,
    uint4* __restrict__ xpack, float* __restrict__ aldst, int N)
{
    __shared__ float Ws[C * HC];
    __shared__ float as_s[HC], ad_s[HC];
    const int t = threadIdx.x;
    for (int i = t; i < C * HC; i += 256) Ws[i] = W[i];
    if (t < HC) { as_s[t] = asrc[t]; ad_s[t] = adst[t]; }
    __syncthreads();
    int n = blockIdx.x * 256 + t;
    if (n >= N) return;
    float xr[C];
    #pragma unroll
    for (int c2 = 0; c2 < C; ++c2) xr[c2] = h1[(size_t)n * C + c2];
    #pragma unroll
    for (int h = 0; h < H; ++h) {
        float v[C], s1 = 0.f, s2 = 0.f;
        #pragma unroll
        for (int c2 = 0; c2 < C; ++c2) {
            float acc = 0.f;
            #pragma unroll
            for (int k = 0; k < C; ++k)
                acc = fmaf(xr[k], Ws[k * HC + h * C + c2], acc);
            v[c2] = acc;
            s1 = fmaf(acc, as_s[h * C + c2], s1);
            s2 = fmaf(acc, ad_s[h * C + c2], s2);
        }
        uint4 pk;
        pk.x = hpk(v[0], v[1]);
        pk.y = hpk(v[2], v[3]);
        pk.z = hpk(v[4], v[5]);
        pk.w = hpk(v[6], s1 * LOG2E);
        int pass = (h >= C) ? 1 : 0;
        int slot = h - pass * C;
        xpack[((size_t)pass * N + n) * 8 + slot] = pk;
        aldst[(size_t)n * H + h] = s2 * LOG2E;
    }
}

// ---------------- fused aggregation: head-split, wave per node ----------------
// Two passes per layer over head groups {0..6} / {7..13}. Per pass: working set
// = 12.8 MB (vs 22.4), and each node-pass record = 128 B = exactly 2 aligned
// cache lines (vs 4). lane = e8*8 + h7: 8 edge slots x 8 head lanes (7 active).
// Fixed shift K = leaky(ld+2) keeps partial den/max linear-combinable across
// edge slots (shfl_xor 8,16,32); head-sum via shfl_xor 1,2,4; cross-pass
// combine through f32 psum[n][c].
#define AGG_STEP(DEN, REC)                                              \
    {                                                                   \
        float l = hhi((REC).w) + ld;                                    \
        float p = __builtin_amdgcn_exp2f(fmaxf(l, 0.2f * l) - K);       \
        DEN += p;                                                       \
        _Float16 ph = (_Float16)p;                                      \
        h2 p2 = { ph, ph };                                             \
        m0 = __builtin_elementwise_max(m0, p2 * u2h((REC).x));          \
        m1 = __builtin_elementwise_max(m1, p2 * u2h((REC).y));          \
        m2 = __builtin_elementwise_max(m2, p2 * u2h((REC).z));          \
        m3 = __builtin_elementwise_max(m3, p2 * u2h((REC).w));          \
    }

template<int LAYER, int PASS>
__global__ __launch_bounds__(256) void k_agg7(
    const int* __restrict__ row_ptr, const int* __restrict__ col,
    const uint4* __restrict__ xp,      // already offset to this pass's bank
    const float* __restrict__ aldst, const float* __restrict__ bias,
    float* __restrict__ psum,
    float* __restrict__ h1, float* __restrict__ out, int N)
{
    const int t    = threadIdx.x;
    const int lane = t & 63;
    const int e8   = lane >> 3;          // edge slot 0..7
    const int h7   = lane & 7;           // head slot (active if < 7)
    const int n    = blockIdx.x * 4 + (t >> 6);
    const bool act = (h7 < C) && (n < N);

    float den = 0.f, den2 = 0.f;
    h2 m0 = u2h(0xFC00FC00u), m1 = m0, m2 = m0, m3 = m0;   // -inf packed
    float ld = 0.f, K = 0.f;

    if (act) {
        const int e0  = row_ptr[n];
        const int deg = row_ptr[n + 1] - e0;
        ld = aldst[(size_t)n * H + PASS * C + h7];           // already * log2e
        float kb = ld + 2.0f * LOG2E;
        K = fmaxf(kb, 0.2f * kb);                            // leaky(ld+2), log2 domain

        if (e8 == 0) {                                       // implicit self loop (once)
            uint4 pk = xp[(size_t)n * 8 + h7];
            float l = hhi(pk.w) + ld;
            float p = __builtin_amdgcn_exp2f(fmaxf(l, 0.2f * l) - K);
            den = p;
            _Float16 ph = (_Float16)p;
            h2 p2 = { ph, ph };
            m0 = p2 * u2h(pk.x);
            m1 = p2 * u2h(pk.y);
            m2 = p2 * u2h(pk.z);
            m3 = p2 * u2h(pk.w);                             // hi half ignored later
        }

        if (deg > 0) {
            const int last = deg - 1;
            int i = e8;                                      // edges i = e8 + 8k
            int c0 = col[e0 + min(i,      last)];
            int c1 = col[e0 + min(i + 8,  last)];
            uint4 r0 = xp[(size_t)c0 * 8 + h7];
            uint4 r1 = xp[(size_t)c1 * 8 + h7];
            c0 = col[e0 + min(i + 16, last)];
            c1 = col[e0 + min(i + 24, last)];
            for (; i < deg; i += 16) {
                uint4 curA = r0, curB = r1;
                r0 = xp[(size_t)c0 * 8 + h7];
                r1 = xp[(size_t)c1 * 8 + h7];
                c0 = col[e0 + min(i + 32, last)];
                c1 = col[e0 + min(i + 40, last)];
                AGG_STEP(den,  curA);                        // edge i
                if (i + 8 < deg) AGG_STEP(den2, curB);       // edge i+8
            }
        }
    }
    den += den2;

    // ---- combine across 8 edge slots ----
    den += __shfl_xor(den, 8, 64);
    den += __shfl_xor(den, 16, 64);
    den += __shfl_xor(den, 32, 64);
    m0 = hshfl_max(m0, 8); m0 = hshfl_max(m0, 16); m0 = hshfl_max(m0, 32);
    m1 = hshfl_max(m1, 8); m1 = hshfl_max(m1, 16); m1 = hshfl_max(m1, 32);
    m2 = hshfl_max(m2, 8); m2 = hshfl_max(m2, 16); m2 = hshfl_max(m2, 32);
    m3 = hshfl_max(m3, 8); m3 = hshfl_max(m3, 16); m3 = hshfl_max(m3, 32);

    float v[C];
    if (act) {
        float rd = 1.f / den;                                // den >= p_self > 0
        v[0] = (float)m0.x * rd; v[1] = (float)m0.y * rd;
        v[2] = (float)m1.x * rd; v[3] = (float)m1.y * rd;
        v[4] = (float)m2.x * rd; v[5] = (float)m2.y * rd;
        v[6] = (float)m3.x * rd;
    } else {
        #pragma unroll
        for (int c = 0; c < C; ++c) v[c] = 0.f;
    }

    // ---- head sum across the 8-lane group (lane h7==7 contributes 0) ----
    #pragma unroll
    for (int off = 1; off <= 4; off <<= 1) {
        #pragma unroll
        for (int c = 0; c < C; ++c) v[c] += __shfl_xor(v[c], off, 64);
    }

    if (n >= N) return;

    if (PASS == 0) {
        if (lane < C) {
            float myv = v[0];
            #pragma unroll
            for (int c = 1; c < C; ++c) if (lane == c) myv = v[c];
            psum[(size_t)n * 8 + lane] = myv;
        }
    } else {
        float o[C];
        #pragma unroll
        for (int c = 0; c < C; ++c)
            o[c] = (v[c] + psum[(size_t)n * 8 + c]) * (1.f / H) + bias[c];
        if (LAYER == 1) {
            if (lane < C) {
                float myo = o[0];
                #pragma unroll
                for (int c = 1; c < C; ++c) if (lane == c) myo = o[c];
                h1[(size_t)n * C + lane] = fmaxf(myo, 0.f);
            }
        } else {
            float mv = o[0];
            #pragma unroll
            for (int c = 1; c < C; ++c) mv = fmaxf(mv, o[c]);
            float lse = 0.f;
            #pragma unroll
            for (int c = 0; c < C; ++c) lse += __expf(o[c] - mv);
            lse = logf(lse);
            if (lane < C) {
                float myo = o[0];
                #pragma unroll
                for (int c = 1; c < C; ++c) if (lane == c) myo = o[c];
                out[(size_t)n * C + lane] = myo - mv - lse;
            }
        }
    }
}

// ---------------- launch ----------------

static inline size_t align16(size_t v) { return (v + 15) & ~(size_t)15; }

extern "C" void kernel_launch(void* const* d_in, const int* in_sizes, int n_in,
                              void* d_out, int out_size, void* d_ws, size_t ws_size,
                              hipStream_t stream)
{
    const float* x     = (const float*)d_in[0];
    const int*   ei    = (const int*)d_in[1];
    const float* W1    = (const float*)d_in[2];
    const float* asrc1 = (const float*)d_in[3];
    const float* adst1 = (const float*)d_in[4];
    const float* b1    = (const float*)d_in[5];
    const float* W2    = (const float*)d_in[6];
    const float* asrc2 = (const float*)d_in[7];
    const float* adst2 = (const float*)d_in[8];
    const float* b2    = (const float*)d_in[9];

    const int N  = in_sizes[0] / FIN;   // 100000
    const int E  = in_sizes[1] / 2;     // 1600000
    const int nb = (N + BSIZE - 1) >> BSHIFT;   // 196

    char* w = (char*)d_ws;
    uint4* xpack   = (uint4*)w; w += align16((size_t)N * 16 * 16);  // 25.6 MB (2 passes x 8 slots)
    int2*  pedge   = (int2*)w;  w += align16((size_t)E * 8);        // 12.8 MB
    float* aldst   = (float*)w; w += align16((size_t)N * H * 4);    //  5.6 MB
    float* h1      = (float*)w; w += align16((size_t)N * C * 4);    //  2.8 MB
    int*   row_ptr = (int*)w;   w += align16((size_t)(N + 1) * 4);
    int*   col     = (int*)w;   w += align16((size_t)E * 4);        //  6.4 MB
    int*   gcnt    = (int*)w;   w += align16((size_t)nb * 4);
    int*   boff    = (int*)w;   w += align16((size_t)(nb + 1) * 4);
    int*   bcur    = (int*)w;   w += align16((size_t)nb * 4);
    unsigned short* WtG = (unsigned short*)w; w += align16((size_t)WT_ROWS * FIN * 2);

    float* psum = (float*)pedge;        // pedge dead after k_bcsr; reuse (3.2 MB < 12.8)
    const uint4* xpA = xpack;                       // heads 0..6 bank
    const uint4* xpB = xpack + (size_t)N * 8;       // heads 7..13 bank

    const int gAgg  = (N + 3) / 4;      // one wave per node, 4 waves/block
    const int gMfma = (N + 63) / 64;
    const int g256N = (N + 255) / 256;

    // ---- bucketed CSR build (no self loops; rebuilt every call) ----
    k_zero<<<1, 256, 0, stream>>>(gcnt, nb);
    k_hist<<<256, 256, 0, stream>>>(ei, E, gcnt, nb);
    k_bscan<<<1, 1024, 0, stream>>>(gcnt, boff, bcur, row_ptr, nb, N);
    k_part<<<256, 256, 0, stream>>>(ei, E, bcur, pedge, nb);
    k_bcsr<<<nb, 512, 0, stream>>>(pedge, boff, row_ptr, col, N);

    // ---- layer 1 ----
    k_convW<<<(WT_ROWS * FIN + 255) / 256, 256, 0, stream>>>(W1, WtG);
    k_proj1_mfma<<<gMfma, 256, 0, stream>>>(x, WtG, asrc1, adst1, xpack, aldst, N);
    k_agg7<1, 0><<<gAgg, 256, 0, stream>>>(row_ptr, col, xpA, aldst, b1, psum,
                                           h1, (float*)d_out, N);
    k_agg7<1, 1><<<gAgg, 256, 0, stream>>>(row_ptr, col, xpB, aldst, b1, psum,
                                           h1, (float*)d_out, N);
    // ---- layer 2 ----
    k_proj2_pack<<<g256N, 256, 0, stream>>>(h1, W2, asrc2, adst2, xpack, aldst, N);
    k_agg7<2, 0><<<gAgg, 256, 0, stream>>>(row_ptr, col, xpA, aldst, b2, psum,
                                           h1, (float*)d_out, N);
    k_agg7<2, 1><<<gAgg, 256, 0, stream>>>(row_ptr, col, xpB, aldst, b2, psum,
                                           h1, (float*)d_out, N);
}

// Round 6
// 409.028 us; speedup vs baseline: 1.1965x; 1.1965x over previous
//
#include <hip/hip_runtime.h>
#include <math.h>

#define H  14
#define C  7
#define HC 98
#define FIN 256
#define NEG_SLOPE 0.2f
#define LOG2E 1.44269504088896f

#define BSHIFT 9
#define BSIZE  512
#define NBUCK_MAX 256

typedef __attribute__((ext_vector_type(8))) short short8;
typedef __attribute__((ext_vector_type(4))) float floatx4;
typedef _Float16 h2 __attribute__((ext_vector_type(2)));

#define WT_ROWS   112            // 98 cols zero-padded to 7*16
#define WT_STRIDE 264            // 256 + 8 pad (bf16 units)
#define VS_STRIDE 99             // 98 + 1 pad (f32 units)

// f32 -> bf16 bits, round-to-nearest-even (MFMA staging only)
__device__ __forceinline__ unsigned bf16r(float f) {
    unsigned u = __float_as_uint(f);
    return (u + 0x7FFFu + ((u >> 16) & 1u)) >> 16;
}

// ---- fp16 helpers via native _Float16 vectors (no hip_fp16.h dependence) ----
__device__ __forceinline__ h2 u2h(unsigned u) { return __builtin_bit_cast(h2, u); }
__device__ __forceinline__ unsigned hpk(float a, float b) {
    h2 v = { (_Float16)a, (_Float16)b };
    return __builtin_bit_cast(unsigned, v);
}
__device__ __forceinline__ float hhi(unsigned w) {
    unsigned short s = (unsigned short)(w >> 16);
    return (float)__builtin_bit_cast(_Float16, s);
}
// max-combine of packed fp16 pair across lanes (xor mask)
__device__ __forceinline__ h2 hshfl_max(h2 v, int mask) {
    int u = __builtin_bit_cast(int, v);
    int o = __shfl_xor(u, mask, 64);
    return __builtin_elementwise_max(v, u2h((unsigned)o));
}

// ---------------- bucketed CSR construction (no self loops) ----------------

__global__ void k_zero(int* __restrict__ p, int n) {
    int i = blockIdx.x * blockDim.x + threadIdx.x;
    if (i < n) p[i] = 0;
}

__global__ __launch_bounds__(256) void k_hist(const int* __restrict__ ei, int E,
                                              int* __restrict__ gcnt, int nb) {
    __shared__ int hist[NBUCK_MAX];
    const int t = threadIdx.x;
    for (int i = t; i < nb; i += 256) hist[i] = 0;
    __syncthreads();
    const int stride = gridDim.x * 256;
    for (int e = blockIdx.x * 256 + t; e < E; e += stride)
        atomicAdd(&hist[ei[E + e] >> BSHIFT], 1);
    __syncthreads();
    for (int i = t; i < nb; i += 256)
        if (hist[i]) atomicAdd(gcnt + i, hist[i]);
}

__global__ __launch_bounds__(1024) void k_bscan(const int* __restrict__ gcnt,
                                                int* __restrict__ boff, int* __restrict__ bcur,
                                                int* __restrict__ row_ptr, int nb, int N) {
    __shared__ int sd[1024];
    int t = threadIdx.x;
    int own = (t < nb) ? gcnt[t] : 0;
    sd[t] = own;
    __syncthreads();
    #pragma unroll
    for (int off = 1; off < 1024; off <<= 1) {
        int v = (t >= off) ? sd[t - off] : 0;
        __syncthreads();
        sd[t] += v;
        __syncthreads();
    }
    if (t < nb) {
        boff[t + 1] = sd[t];
        bcur[t] = sd[t] - own;          // exclusive
        if (t == nb - 1) row_ptr[N] = sd[t];
    }
    if (t == 0) boff[0] = 0;
}

__global__ __launch_bounds__(256) void k_part(const int* __restrict__ ei, int E,
                                              int* __restrict__ bcur, int2* __restrict__ pedge,
                                              int nb) {
    __shared__ int hist[NBUCK_MAX];
    __shared__ int start[NBUCK_MAX];
    const int t = threadIdx.x;
    const int chunk = (E + gridDim.x - 1) / gridDim.x;
    const int c0 = blockIdx.x * chunk;
    const int c1 = min(c0 + chunk, E);
    for (int i = t; i < nb; i += 256) hist[i] = 0;
    __syncthreads();
    for (int e = c0 + t; e < c1; e += 256)
        atomicAdd(&hist[ei[E + e] >> BSHIFT], 1);
    __syncthreads();
    for (int i = t; i < nb; i += 256) {
        int h = hist[i];
        start[i] = h ? atomicAdd(bcur + i, h) : 0;
        hist[i] = 0;                     // reuse as local cursor
    }
    __syncthreads();
    for (int e = c0 + t; e < c1; e += 256) {
        int s = ei[e], d = ei[E + e];
        int b = d >> BSHIFT;
        int pos = start[b] + atomicAdd(&hist[b], 1);
        pedge[pos] = make_int2(s, d);
    }
}

__global__ __launch_bounds__(512) void k_bcsr(const int2* __restrict__ pedge,
                                              const int* __restrict__ boff,
                                              int* __restrict__ row_ptr, int* __restrict__ col,
                                              int N) {
    __shared__ int cnt[BSIZE];
    __shared__ int sc[BSIZE];
    __shared__ int cur[BSIZE];
    const int b  = blockIdx.x;
    const int t  = threadIdx.x;
    const int e0 = boff[b], e1 = boff[b + 1];
    const int base = b << BSHIFT;
    const int nv = min(BSIZE, N - base);
    cnt[t] = 0;
    __syncthreads();
    for (int e = e0 + t; e < e1; e += 512)
        atomicAdd(&cnt[pedge[e].y - base], 1);
    __syncthreads();
    sc[t] = cnt[t];
    __syncthreads();
    #pragma unroll
    for (int off = 1; off < BSIZE; off <<= 1) {
        int v = (t >= off) ? sc[t - off] : 0;
        __syncthreads();
        sc[t] += v;
        __syncthreads();
    }
    if (t < nv) {
        int excl = sc[t] - cnt[t];
        row_ptr[base + t] = e0 + excl;
        cur[t] = excl;
    }
    __syncthreads();
    for (int e = e0 + t; e < e1; e += 512) {
        int2 r = pedge[e];
        int d = r.y - base;
        int pos = e0 + atomicAdd(&cur[d], 1);
        col[pos] = r.x;
    }
}

// ---------------- layer-1: MFMA projection fused with pack ----------------

__global__ void k_convW(const float* __restrict__ W, unsigned short* __restrict__ WtG) {
    int id = blockIdx.x * blockDim.x + threadIdx.x;   // 112*256
    int n = id >> 8, k = id & 255;
    float v = (n < HC) ? W[k * HC + n] : 0.f;
    WtG[id] = (unsigned short)(__float_as_uint(v) >> 16);  // exact: inputs bf16-rounded
}

// Barrier-free K-loop: A-fragments loaded global->reg per lane (no x staging,
// no per-step barriers). Weights staged once in LDS; LDS reused for the
// output transpose after the K-loop.
// xpack[n*H+h] = {7 msg fp16, src-logit*log2e fp16}; aldst = dst logit*log2e.
__global__ __launch_bounds__(256) void k_proj1_mfma(
    const float* __restrict__ x, const unsigned short* __restrict__ WtG,
    const float* __restrict__ asrc, const float* __restrict__ adst,
    uint4* __restrict__ xpack, float* __restrict__ aldst, int N)
{
    __shared__ unsigned short wt_s[WT_ROWS * WT_STRIDE];  // 59136 B (reused as f32 vals)
    __shared__ float as_s[HC], ad_s[HC];
    float* vals_s = (float*)wt_s;                          // 64*99*4 = 25344 B < 59136
    const int t  = threadIdx.x;
    const int wv = t >> 6;
    const int l  = t & 63;
    const int ln = l & 15;
    const int qd = l >> 4;
    const int rowBase = blockIdx.x * 64;

    #pragma unroll
    for (int i = 0; i < 14; ++i) {
        int f = i * 256 + t;            // uint4 index, 3584 total (32 per row)
        int r = f >> 5, pos = f & 31;
        *(uint4*)(wt_s + r * WT_STRIDE + pos * 8) = ((const uint4*)WtG)[f];
    }
    if (t < HC) { as_s[t] = asrc[t]; ad_s[t] = adst[t]; }
    __syncthreads();

    // my MFMA A-row: rowBase + wv*16 + ln (clamped; pack loop guards gn >= N)
    int gr = rowBase + (wv << 4) + ln; if (gr >= N) gr = N - 1;
    const float* xr = x + (size_t)gr * FIN;

    // load all 8 steps' A-fragments: step s -> cols s*32 + qd*8 .. +7
    short8 afr[8];
    #pragma unroll
    for (int s = 0; s < 8; ++s) {
        float4 v0 = *(const float4*)(xr + s * 32 + qd * 8);
        float4 v1 = *(const float4*)(xr + s * 32 + qd * 8 + 4);
        short8 a;
        a[0] = (short)(__float_as_uint(v0.x) >> 16);
        a[1] = (short)(__float_as_uint(v0.y) >> 16);
        a[2] = (short)(__float_as_uint(v0.z) >> 16);
        a[3] = (short)(__float_as_uint(v0.w) >> 16);
        a[4] = (short)(__float_as_uint(v1.x) >> 16);
        a[5] = (short)(__float_as_uint(v1.y) >> 16);
        a[6] = (short)(__float_as_uint(v1.z) >> 16);
        a[7] = (short)(__float_as_uint(v1.w) >> 16);
        afr[s] = a;
    }

    floatx4 acc[7] = {};
    #pragma unroll
    for (int s = 0; s < 8; ++s) {
        const int k0 = s * 32;
        #pragma unroll
        for (int ct = 0; ct < 7; ++ct) {
            short8 b = *(const short8*)(wt_s + (ct * 16 + ln) * WT_STRIDE + k0 + qd * 8);
            acc[ct] = __builtin_amdgcn_mfma_f32_16x16x32_bf16(afr[s], b, acc[ct], 0, 0, 0);
        }
    }

    __syncthreads();                    // all waves done with wt_s; reuse as vals_s
    // C/D: col = ln, row = qd*4 + r (local row = wv*16 + qd*4 + r)
    #pragma unroll
    for (int ct = 0; ct < 7; ++ct) {
        int colg = ct * 16 + ln;
        if (colg < HC) {
            #pragma unroll
            for (int r = 0; r < 4; ++r)
                vals_s[((wv << 4) + (qd << 2) + r) * VS_STRIDE + colg] = acc[ct][r];
        }
    }
    __syncthreads();

    // pack: 64 nodes x 14 heads = 896 records
    for (int p = t; p < 64 * H; p += 256) {
        int nl = p / H, h = p - nl * H;
        int gn = rowBase + nl;
        if (gn >= N) break;
        const float* vp = vals_s + nl * VS_STRIDE + h * C;
        float v[C];
        float s1 = 0.f, s2 = 0.f;
        #pragma unroll
        for (int c2 = 0; c2 < C; ++c2) {
            float f = vp[c2];
            v[c2] = f;
            s1 = fmaf(f, as_s[h * C + c2], s1);
            s2 = fmaf(f, ad_s[h * C + c2], s2);
        }
        uint4 pk;
        pk.x = hpk(v[0], v[1]);
        pk.y = hpk(v[2], v[3]);
        pk.z = hpk(v[4], v[5]);
        pk.w = hpk(v[6], s1 * LOG2E);
        xpack[(size_t)gn * H + h] = pk;
        aldst[(size_t)gn * H + h] = s2 * LOG2E;
    }
}

// ---------------- layer-2 projection + pack (thread per node) ----------------

__global__ __launch_bounds__(256) void k_proj2_pack(
    const float* __restrict__ h1, const float* __restrict__ W,
    const float* __restrict__ asrc, const float* __restrict__ adst,
    uint4* __restrict__ xpack, float* __restrict__ aldst, int N)
{
    __shared__ float Ws[C * HC];
    __shared__ float as_s[HC], ad_s[HC];
    const int t = threadIdx.x;
    for (int i = t; i < C * HC; i += 256) Ws[i] = W[i];
    if (t < HC) { as_s[t] = asrc[t]; ad_s[t] = adst[t]; }
    __syncthreads();
    int n = blockIdx.x * 256 + t;
    if (n >= N) return;
    float xr[C];
    #pragma unroll
    for (int c2 = 0; c2 < C; ++c2) xr[c2] = h1[(size_t)n * C + c2];
    #pragma unroll
    for (int h = 0; h < H; ++h) {
        float v[C], s1 = 0.f, s2 = 0.f;
        #pragma unroll
        for (int c2 = 0; c2 < C; ++c2) {
            float acc = 0.f;
            #pragma unroll
            for (int k = 0; k < C; ++k)
                acc = fmaf(xr[k], Ws[k * HC + h * C + c2], acc);
            v[c2] = acc;
            s1 = fmaf(acc, as_s[h * C + c2], s1);
            s2 = fmaf(acc, ad_s[h * C + c2], s2);
        }
        uint4 pk;
        pk.x = hpk(v[0], v[1]);
        pk.y = hpk(v[2], v[3]);
        pk.z = hpk(v[4], v[5]);
        pk.w = hpk(v[6], s1 * LOG2E);
        xpack[(size_t)n * H + h] = pk;     // 224 B contiguous per thread
        aldst[(size_t)n * H + h] = s2 * LOG2E;
    }
}

// ---------------- fused aggregation: ONE WAVE PER NODE ----------------
// lane = e4*16 + h: e4 in 0..3 = edge slot, h in 0..15 = head (h<14 active).
// Fixed shift K = leaky(ld+2) makes softmax state LINEAR: partial den sums
// and partial channel-maxes combine across edge slots via shfl_xor(16,32);
// head-mean then reduces via shfl_xor(1,2,4,8). No LDS, no __syncthreads,
// serial gather chain per lane = deg/4 instead of deg.
#define AGG_STEP(DEN, REC)                                              \
    {                                                                   \
        float l = hhi((REC).w) + ld;                                    \
        float p = __builtin_amdgcn_exp2f(fmaxf(l, 0.2f * l) - K);       \
        DEN += p;                                                       \
        _Float16 ph = (_Float16)p;                                      \
        h2 p2 = { ph, ph };                                             \
        m0 = __builtin_elementwise_max(m0, p2 * u2h((REC).x));          \
        m1 = __builtin_elementwise_max(m1, p2 * u2h((REC).y));          \
        m2 = __builtin_elementwise_max(m2, p2 * u2h((REC).z));          \
        m3 = __builtin_elementwise_max(m3, p2 * u2h((REC).w));          \
    }

template<int LAYER>
__global__ __launch_bounds__(256) void k_agg(
    const int* __restrict__ row_ptr, const int* __restrict__ col,
    const uint4* __restrict__ xpack, const float* __restrict__ aldst,
    const float* __restrict__ bias,
    float* __restrict__ h1, float* __restrict__ out, int N)
{
    const int t    = threadIdx.x;
    const int lane = t & 63;
    const int e4   = lane >> 4;          // edge slot 0..3
    const int h    = lane & 15;          // head slot (active if < 14)
    const int n    = blockIdx.x * 4 + (t >> 6);
    const bool act = (h < H) && (n < N);

    float den = 0.f, den2 = 0.f;
    h2 m0 = u2h(0xFC00FC00u), m1 = m0, m2 = m0, m3 = m0;   // -inf packed
    float ld = 0.f, K = 0.f;

    if (act) {
        const int e0  = row_ptr[n];
        const int deg = row_ptr[n + 1] - e0;
        ld = aldst[(size_t)n * H + h];                     // already * log2e
        float kb = ld + 2.0f * LOG2E;
        K = fmaxf(kb, 0.2f * kb);                          // leaky(ld+2), log2 domain

        if (e4 == 0) {                                     // implicit self loop (once)
            uint4 pk = xpack[(size_t)n * H + h];
            float l = hhi(pk.w) + ld;
            float p = __builtin_amdgcn_exp2f(fmaxf(l, 0.2f * l) - K);
            den = p;
            _Float16 ph = (_Float16)p;
            h2 p2 = { ph, ph };
            m0 = p2 * u2h(pk.x);
            m1 = p2 * u2h(pk.y);
            m2 = p2 * u2h(pk.z);
            m3 = p2 * u2h(pk.w);                           // hi half ignored later
        }

        if (deg > 0) {
            const int last = deg - 1;
            int i = e4;                                    // edges i = e4 + 4k
            int c0 = col[e0 + min(i,      last)];
            int c1 = col[e0 + min(i + 4,  last)];
            uint4 r0 = xpack[(size_t)c0 * H + h];
            uint4 r1 = xpack[(size_t)c1 * H + h];
            c0 = col[e0 + min(i + 8,  last)];
            c1 = col[e0 + min(i + 12, last)];
            for (; i < deg; i += 8) {
                uint4 curA = r0, curB = r1;
                r0 = xpack[(size_t)c0 * H + h];
                r1 = xpack[(size_t)c1 * H + h];
                c0 = col[e0 + min(i + 16, last)];
                c1 = col[e0 + min(i + 20, last)];
                AGG_STEP(den,  curA);                      // edge i
                if (i + 4 < deg) AGG_STEP(den2, curB);     // edge i+4
            }
        }
    }
    den += den2;

    // ---- combine across edge slots (lanes h, h+16, h+32, h+48) ----
    den += __shfl_xor(den, 16, 64);
    den += __shfl_xor(den, 32, 64);
    m0 = hshfl_max(m0, 16); m0 = hshfl_max(m0, 32);
    m1 = hshfl_max(m1, 16); m1 = hshfl_max(m1, 32);
    m2 = hshfl_max(m2, 16); m2 = hshfl_max(m2, 32);
    m3 = hshfl_max(m3, 16); m3 = hshfl_max(m3, 32);

    float v[C];
    if (act) {
        float rd = 1.f / den;                              // den >= p_self > 0
        v[0] = (float)m0.x * rd; v[1] = (float)m0.y * rd;
        v[2] = (float)m1.x * rd; v[3] = (float)m1.y * rd;
        v[4] = (float)m2.x * rd; v[5] = (float)m2.y * rd;
        v[6] = (float)m3.x * rd;
    } else {
        #pragma unroll
        for (int c = 0; c < C; ++c) v[c] = 0.f;
    }

    // ---- head mean across 16-lane group ----
    #pragma unroll
    for (int off = 1; off <= 8; off <<= 1) {
        #pragma unroll
        for (int c = 0; c < C; ++c) v[c] += __shfl_xor(v[c], off, 64);
    }

    if (n >= N) return;
    if (LAYER == 1) {
        if (lane < C) {
            float myv = v[0];
            #pragma unroll
            for (int c = 1; c < C; ++c) if (lane == c) myv = v[c];
            h1[(size_t)n * C + lane] = fmaxf(myv * (1.f / H) + bias[lane], 0.f);
        }
    } else {
        float o[C];
        #pragma unroll
        for (int c = 0; c < C; ++c) o[c] = v[c] * (1.f / H) + bias[c];
        float mv = o[0];
        #pragma unroll
        for (int c = 1; c < C; ++c) mv = fmaxf(mv, o[c]);
        float lse = 0.f;
        #pragma unroll
        for (int c = 0; c < C; ++c) lse += __expf(o[c] - mv);
        lse = logf(lse);
        if (lane < C) {
            float myo = o[0];
            #pragma unroll
            for (int c = 1; c < C; ++c) if (lane == c) myo = o[c];
            out[(size_t)n * C + lane] = myo - mv - lse;
        }
    }
}

// ---------------- launch ----------------

static inline size_t align16(size_t v) { return (v + 15) & ~(size_t)15; }

extern "C" void kernel_launch(void* const* d_in, const int* in_sizes, int n_in,
                              void* d_out, int out_size, void* d_ws, size_t ws_size,
                              hipStream_t stream)
{
    const float* x     = (const float*)d_in[0];
    const int*   ei    = (const int*)d_in[1];
    const float* W1    = (const float*)d_in[2];
    const float* asrc1 = (const float*)d_in[3];
    const float* adst1 = (const float*)d_in[4];
    const float* b1    = (const float*)d_in[5];
    const float* W2    = (const float*)d_in[6];
    const float* asrc2 = (const float*)d_in[7];
    const float* adst2 = (const float*)d_in[8];
    const float* b2    = (const float*)d_in[9];

    const int N  = in_sizes[0] / FIN;   // 100000
    const int E  = in_sizes[1] / 2;     // 1600000
    const int nb = (N + BSIZE - 1) >> BSHIFT;   // 196

    char* w = (char*)d_ws;
    uint4* xpack   = (uint4*)w; w += align16((size_t)N * H * 16);   // 22.4 MB
    int2*  pedge   = (int2*)w;  w += align16((size_t)E * 8);        // 12.8 MB
    float* aldst   = (float*)w; w += align16((size_t)N * H * 4);    //  5.6 MB
    float* h1      = (float*)w; w += align16((size_t)N * C * 4);    //  2.8 MB
    int*   row_ptr = (int*)w;   w += align16((size_t)(N + 1) * 4);
    int*   col     = (int*)w;   w += align16((size_t)E * 4);        //  6.4 MB
    int*   gcnt    = (int*)w;   w += align16((size_t)nb * 4);
    int*   boff    = (int*)w;   w += align16((size_t)(nb + 1) * 4);
    int*   bcur    = (int*)w;   w += align16((size_t)nb * 4);
    unsigned short* WtG = (unsigned short*)w; w += align16((size_t)WT_ROWS * FIN * 2);

    const int gAgg  = (N + 3) / 4;      // one wave per node, 4 waves/block
    const int gMfma = (N + 63) / 64;
    const int g256N = (N + 255) / 256;

    // ---- bucketed CSR build (no self loops; rebuilt every call) ----
    k_zero<<<1, 256, 0, stream>>>(gcnt, nb);
    k_hist<<<256, 256, 0, stream>>>(ei, E, gcnt, nb);
    k_bscan<<<1, 1024, 0, stream>>>(gcnt, boff, bcur, row_ptr, nb, N);
    k_part<<<256, 256, 0, stream>>>(ei, E, bcur, pedge, nb);
    k_bcsr<<<nb, 512, 0, stream>>>(pedge, boff, row_ptr, col, N);

    // ---- layer 1 ----
    k_convW<<<(WT_ROWS * FIN + 255) / 256, 256, 0, stream>>>(W1, WtG);
    k_proj1_mfma<<<gMfma, 256, 0, stream>>>(x, WtG, asrc1, adst1, xpack, aldst, N);
    k_agg<1><<<gAgg, 256, 0, stream>>>(row_ptr, col, xpack, aldst, b1,
                                       h1, (float*)d_out, N);
    // ---- layer 2 ----
    k_proj2_pack<<<g256N, 256, 0, stream>>>(h1, W2, asrc2, adst2, xpack, aldst, N);
    k_agg<2><<<gAgg, 256, 0, stream>>>(row_ptr, col, xpack, aldst, b2,
                                       h1, (float*)d_out, N);
}